// Round 13
// baseline (10727.721 us; speedup 1.0000x reference)
//
#include <hip/hip_runtime.h>
#include <cmath>

#define NE   16
#define DIN  256
#define DHID 512
#define NROW 524288
#define ROWS 64
#define TAU  4e-4f

typedef __bf16 bf16;
typedef bf16  bf16x8 __attribute__((ext_vector_type(8)));
typedef float f32x4  __attribute__((ext_vector_type(4)));

template<int CTRL>
__device__ __forceinline__ float dpp_xor_add(float v) {
    int s = __builtin_amdgcn_update_dpp(0, __float_as_int(v), CTRL, 0xF, 0xF, true);
    return v + __int_as_float(s);
}
template<int OFF>
__device__ __forceinline__ float swz_xor_add(float v) {
    int s = __builtin_amdgcn_ds_swizzle(__float_as_int(v), OFF);
    return v + __int_as_float(s);
}

// ---- K0: split w1 -> bf16 hi/lo, per-(ch,ksk) slice layout (verbatim r6/r7/r9) ----
__global__ __launch_bounds__(256)
void split_w1_k(const float* __restrict__ w1, bf16* __restrict__ w1t) {
    int i = blockIdx.x * 256 + threadIdx.x;   // 131072 elements
    int col = i & 511, k = i >> 9;
    float v = w1[k * DHID + col];
    bf16 h = (bf16)v;
    bf16 l = (bf16)(v - (float)h);
    int ch = col >> 7, cl = col & 127, ksk = k >> 5, g = (k >> 3) & 3, j = k & 7;
    size_t base = (size_t)(ch * 8 + ksk) * 8192;
    w1t[base +        g * 1024 + cl * 8 + j] = h;
    w1t[base + 4096 + g * 1024 + cl * 8 + j] = l;
}

#define LOADW(W, si)                                                              \
    {                                                                             \
        const bf16* sp = w1t + (size_t)(si) * 8192 + g * 1024 + (64 * wc + c) * 8;\
        _Pragma("unroll")                                                         \
        for (int tj = 0; tj < 4; ++tj) {                                          \
            W[tj][0] = *(const bf16x8*)(sp + tj * 128);                           \
            W[tj][1] = *(const bf16x8*)(sp + tj * 128 + 4096);                    \
        }                                                                         \
    }

#define LOADX(X, kk)                                                              \
    {                                                                             \
        _Pragma("unroll")                                                         \
        for (int ti = 0; ti < 2; ++ti) {                                          \
            X[ti][0] = *(const bf16x8*)&xh_s[kk][g][32 * wr + 16 * ti + c][0];    \
            X[ti][1] = *(const bf16x8*)&xl_s[kk][g][32 * wr + 16 * ti + c][0];    \
        }                                                                         \
    }

#define COMPUTE(X, W)                                                             \
    {                                                                             \
        _Pragma("unroll")                                                         \
        for (int tj = 0; tj < 4; ++tj)                                            \
            _Pragma("unroll")                                                     \
            for (int ti = 0; ti < 2; ++ti) {                                      \
                acc[ti][tj] = __builtin_amdgcn_mfma_f32_16x16x32_bf16(X[ti][0], W[tj][0], acc[ti][tj], 0, 0, 0); \
                acc[ti][tj] = __builtin_amdgcn_mfma_f32_16x16x32_bf16(X[ti][0], W[tj][1], acc[ti][tj], 0, 0, 0); \
                acc[ti][tj] = __builtin_amdgcn_mfma_f32_16x16x32_bf16(X[ti][1], W[tj][0], acc[ti][tj], 0, 0, 0); \
            }                                                                     \
    }

// x staging block (verbatim r9), used by router and all probes
#define STAGE_X()                                                                 \
    {                                                                             \
        const int r = t & 63;                                                     \
        const int q = t >> 6;                                                     \
        const float* xg = x + (row0 + r) * DIN + q * 64;                          \
        _Pragma("unroll")                                                         \
        for (int m = 0; m < 8; ++m) {                                             \
            float4 v0 = ((const float4*)xg)[2 * m];                               \
            float4 v1 = ((const float4*)xg)[2 * m + 1];                           \
            int k   = q * 64 + m * 8;                                             \
            int ksk = k >> 5, gg = (k >> 3) & 3;                                  \
            float vv[8] = {v0.x, v0.y, v0.z, v0.w, v1.x, v1.y, v1.z, v1.w};       \
            bf16 hb[8], lb[8];                                                    \
            _Pragma("unroll")                                                     \
            for (int qq = 0; qq < 8; ++qq) {                                      \
                hb[qq] = (bf16)vv[qq];                                            \
                lb[qq] = (bf16)(vv[qq] - (float)hb[qq]);                          \
            }                                                                     \
            *(bf16x8*)&xh_s[ksk][gg][r][0] = *(const bf16x8*)hb;                  \
            *(bf16x8*)&xl_s[ksk][gg][r][0] = *(const bf16x8*)lb;                  \
        }                                                                         \
    }

// ---- Pass A: verbatim r9 (passed, 1360 us, absmax 4.882812e-4) ----
__global__ __launch_bounds__(256, 2)
void router_mfma_k(const float* __restrict__ x,
                   const float* __restrict__ b1,
                   const float* __restrict__ w2,
                   const float* __restrict__ b2,
                   float* __restrict__ out,
                   const bf16* __restrict__ w1t,
                   unsigned* __restrict__ cnt,
                   unsigned* __restrict__ ids,
                   unsigned cap)
{
    __shared__ __align__(16) bf16 xh_s[8][4][ROWS][8];
    __shared__ __align__(16) bf16 xl_s[8][4][ROWS][8];
    __shared__ float l_lds[ROWS][NE + 1];

    const int t    = threadIdx.x;
    const int lane = t & 63;
    const int wv   = t >> 6;
    const int wr   = wv >> 1;
    const int wc   = wv & 1;
    const int c    = lane & 15;
    const int g    = lane >> 4;
    const long long row0 = (long long)blockIdx.x * ROWS;

    bf16x8 Wb[3][4][2], Xb[2][2][2];
    LOADW(Wb[0], 0);
    LOADW(Wb[1], 1);

    STAGE_X();
    __syncthreads();

    LOADX(Xb[0], 0);

    float lg[8];
#pragma unroll
    for (int i = 0; i < 8; ++i) lg[i] = 0.f;

    f32x4 acc[2][4];

#pragma unroll
    for (int ch = 0; ch < 4; ++ch) {
#pragma unroll
        for (int ti = 0; ti < 2; ++ti)
#pragma unroll
            for (int tj = 0; tj < 4; ++tj)
#pragma unroll
                for (int r = 0; r < 4; ++r) acc[ti][tj][r] = 0.f;

#pragma unroll
        for (int ks = 0; ks < 8; ++ks) {
            const int s  = ch * 8 + ks;
            const int sp2 = (s + 2 > 31) ? 31 : (s + 2);
            LOADW(Wb[(s + 2) % 3], sp2);
            LOADX(Xb[(s + 1) & 1], (s + 1) & 7);
            COMPUTE(Xb[s & 1], Wb[s % 3]);
        }

#pragma unroll
        for (int tj = 0; tj < 4; ++tj) {
            float bj = b1[128 * ch + 64 * wc + 16 * tj + c];
#pragma unroll
            for (int ti = 0; ti < 2; ++ti)
#pragma unroll
                for (int r = 0; r < 4; ++r)
                    acc[ti][tj][r] = fmaxf(acc[ti][tj][r] + bj, 0.f);
        }

#pragma unroll 1
        for (int e = 0; e < NE; ++e) {
            float p[8];
#pragma unroll
            for (int i = 0; i < 8; ++i) p[i] = 0.f;
#pragma unroll
            for (int tj = 0; tj < 4; ++tj) {
                float wvv = w2[(128 * ch + 64 * wc + 16 * tj + c) * NE + e];
#pragma unroll
                for (int ti = 0; ti < 2; ++ti)
#pragma unroll
                    for (int r = 0; r < 4; ++r)
                        p[ti * 4 + r] = fmaf(acc[ti][tj][r], wvv, p[ti * 4 + r]);
            }
#pragma unroll
            for (int i = 0; i < 8; ++i) p[i] = dpp_xor_add<0xB1>(p[i]);
#pragma unroll
            for (int i = 0; i < 8; ++i) p[i] = dpp_xor_add<0x4E>(p[i]);
#pragma unroll
            for (int i = 0; i < 8; ++i) p[i] = swz_xor_add<0x101F>(p[i]);
#pragma unroll
            for (int i = 0; i < 8; ++i) p[i] = swz_xor_add<0x201F>(p[i]);
            if (c == e) {
#pragma unroll
                for (int i = 0; i < 8; ++i) lg[i] += p[i];
            }
        }
    }

    __syncthreads();
    if (wc == 0) {
        float b2c = b2[c];
#pragma unroll
        for (int ti = 0; ti < 2; ++ti)
#pragma unroll
            for (int r = 0; r < 4; ++r)
                l_lds[32 * wr + 16 * ti + 4 * g + r][c] = lg[ti * 4 + r] + b2c;
    }
    __syncthreads();
    if (wc == 1) {
#pragma unroll
        for (int ti = 0; ti < 2; ++ti)
#pragma unroll
            for (int r = 0; r < 4; ++r)
                l_lds[32 * wr + 16 * ti + 4 * g + r][c] += lg[ti * 4 + r];
    }
    __syncthreads();

    if (t < ROWS) {
        float l[NE];
#pragma unroll
        for (int e = 0; e < NE; ++e) l[e] = l_lds[t][e];

        float m1 = -INFINITY; int i1 = 0;
#pragma unroll
        for (int e = 0; e < NE; ++e)
            if (l[e] > m1) { m1 = l[e]; i1 = e; }
        float m2 = -INFINITY; int i2 = -1;
#pragma unroll
        for (int e = 0; e < NE; ++e)
            if (e != i1 && l[e] > m2) { m2 = l[e]; i2 = e; }
        float m3 = -INFINITY;
#pragma unroll
        for (int e = 0; e < NE; ++e)
            if (e != i1 && e != i2 && l[e] > m3) m3 = l[e];

        if (m2 - m3 < TAU) {
            unsigned idx = atomicAdd(cnt, 1u);
            if (idx < cap) ids[idx] = (unsigned)(row0 + t);
        }

        float s[NE];
#pragma unroll
        for (int e = 0; e < NE; ++e)
            s[e] = (e == i1 || e == i2) ? l[e] : 0.f;
        float mx = s[0];
#pragma unroll
        for (int e = 1; e < NE; ++e) mx = fmaxf(mx, s[e]);
        float ex[NE];
        float sum = 0.f;
#pragma unroll
        for (int e = 0; e < NE; ++e) { ex[e] = expf(s[e] - mx); sum += ex[e]; }
        float r = 1.f / sum;
        float4 o0 = {ex[0] * r, ex[1] * r, ex[2] * r, ex[3] * r};
        float4 o1 = {ex[4] * r, ex[5] * r, ex[6] * r, ex[7] * r};
        float4 o2 = {ex[8] * r, ex[9] * r, ex[10] * r, ex[11] * r};
        float4 o3 = {ex[12] * r, ex[13] * r, ex[14] * r, ex[15] * r};
        float4* og = (float4*)(out + (row0 + t) * NE);
        og[0] = o0; og[1] = o1; og[2] = o2; og[3] = o3;
    }
}

// ---- PROBE 1: staging only ----
__global__ __launch_bounds__(256, 2)
void pS_k(const float* __restrict__ x)
{
    __shared__ __align__(16) bf16 xh_s[8][4][ROWS][8];
    __shared__ __align__(16) bf16 xl_s[8][4][ROWS][8];
    __shared__ float l_lds[ROWS][NE + 1];
    const int t = threadIdx.x;
    const long long row0 = (long long)(blockIdx.x & 8191) * ROWS;
    STAGE_X();
    __syncthreads();
    float kp = (float)xh_s[t & 7][0][t & 63][0] + (float)xl_s[(t >> 3) & 7][t & 3][t & 63][1];
    if (t == 255) l_lds[0][0] = kp;
    asm volatile("" :: "v"(kp));
}

// ---- PROBE 2: staging + K-loop (layer-1) + bias/relu; layer-2 removed ----
__global__ __launch_bounds__(256, 2)
void pL1_k(const float* __restrict__ x,
           const float* __restrict__ b1,
           const bf16* __restrict__ w1t)
{
    __shared__ __align__(16) bf16 xh_s[8][4][ROWS][8];
    __shared__ __align__(16) bf16 xl_s[8][4][ROWS][8];
    __shared__ float l_lds[ROWS][NE + 1];

    const int t    = threadIdx.x;
    const int lane = t & 63;
    const int wv   = t >> 6;
    const int wr   = wv >> 1;
    const int wc   = wv & 1;
    const int c    = lane & 15;
    const int g    = lane >> 4;
    const long long row0 = (long long)(blockIdx.x & 8191) * ROWS;

    bf16x8 Wb[3][4][2], Xb[2][2][2];
    LOADW(Wb[0], 0);
    LOADW(Wb[1], 1);
    STAGE_X();
    __syncthreads();
    LOADX(Xb[0], 0);

    f32x4 acc[2][4];
    float kp = 0.f;

#pragma unroll
    for (int ch = 0; ch < 4; ++ch) {
#pragma unroll
        for (int ti = 0; ti < 2; ++ti)
#pragma unroll
            for (int tj = 0; tj < 4; ++tj)
#pragma unroll
                for (int r = 0; r < 4; ++r) acc[ti][tj][r] = 0.f;

#pragma unroll
        for (int ks = 0; ks < 8; ++ks) {
            const int s  = ch * 8 + ks;
            const int sp2 = (s + 2 > 31) ? 31 : (s + 2);
            LOADW(Wb[(s + 2) % 3], sp2);
            LOADX(Xb[(s + 1) & 1], (s + 1) & 7);
            COMPUTE(Xb[s & 1], Wb[s % 3]);
        }

#pragma unroll
        for (int tj = 0; tj < 4; ++tj) {
            float bj = b1[128 * ch + 64 * wc + 16 * tj + c];
#pragma unroll
            for (int ti = 0; ti < 2; ++ti)
#pragma unroll
                for (int r = 0; r < 4; ++r)
                    kp += fmaxf(acc[ti][tj][r] + bj, 0.f);   // fold (keeps MFMAs live)
        }
    }
    if (t == 255) l_lds[0][0] = kp;
    asm volatile("" :: "v"(kp));
}

// ---- PROBE 3: staging + K-loop + bias/relu + verbatim layer-2 ----
__global__ __launch_bounds__(256, 2)
void pL12_k(const float* __restrict__ x,
            const float* __restrict__ b1,
            const float* __restrict__ w2,
            const bf16* __restrict__ w1t)
{
    __shared__ __align__(16) bf16 xh_s[8][4][ROWS][8];
    __shared__ __align__(16) bf16 xl_s[8][4][ROWS][8];
    __shared__ float l_lds[ROWS][NE + 1];

    const int t    = threadIdx.x;
    const int lane = t & 63;
    const int wv   = t >> 6;
    const int wr   = wv >> 1;
    const int wc   = wv & 1;
    const int c    = lane & 15;
    const int g    = lane >> 4;
    const long long row0 = (long long)(blockIdx.x & 8191) * ROWS;

    bf16x8 Wb[3][4][2], Xb[2][2][2];
    LOADW(Wb[0], 0);
    LOADW(Wb[1], 1);
    STAGE_X();
    __syncthreads();
    LOADX(Xb[0], 0);

    float lg[8];
#pragma unroll
    for (int i = 0; i < 8; ++i) lg[i] = 0.f;

    f32x4 acc[2][4];

#pragma unroll
    for (int ch = 0; ch < 4; ++ch) {
#pragma unroll
        for (int ti = 0; ti < 2; ++ti)
#pragma unroll
            for (int tj = 0; tj < 4; ++tj)
#pragma unroll
                for (int r = 0; r < 4; ++r) acc[ti][tj][r] = 0.f;

#pragma unroll
        for (int ks = 0; ks < 8; ++ks) {
            const int s  = ch * 8 + ks;
            const int sp2 = (s + 2 > 31) ? 31 : (s + 2);
            LOADW(Wb[(s + 2) % 3], sp2);
            LOADX(Xb[(s + 1) & 1], (s + 1) & 7);
            COMPUTE(Xb[s & 1], Wb[s % 3]);
        }

#pragma unroll
        for (int tj = 0; tj < 4; ++tj) {
            float bj = b1[128 * ch + 64 * wc + 16 * tj + c];
#pragma unroll
            for (int ti = 0; ti < 2; ++ti)
#pragma unroll
                for (int r = 0; r < 4; ++r)
                    acc[ti][tj][r] = fmaxf(acc[ti][tj][r] + bj, 0.f);
        }

#pragma unroll 1
        for (int e = 0; e < NE; ++e) {
            float p[8];
#pragma unroll
            for (int i = 0; i < 8; ++i) p[i] = 0.f;
#pragma unroll
            for (int tj = 0; tj < 4; ++tj) {
                float wvv = w2[(128 * ch + 64 * wc + 16 * tj + c) * NE + e];
#pragma unroll
                for (int ti = 0; ti < 2; ++ti)
#pragma unroll
                    for (int r = 0; r < 4; ++r)
                        p[ti * 4 + r] = fmaf(acc[ti][tj][r], wvv, p[ti * 4 + r]);
            }
#pragma unroll
            for (int i = 0; i < 8; ++i) p[i] = dpp_xor_add<0xB1>(p[i]);
#pragma unroll
            for (int i = 0; i < 8; ++i) p[i] = dpp_xor_add<0x4E>(p[i]);
#pragma unroll
            for (int i = 0; i < 8; ++i) p[i] = swz_xor_add<0x101F>(p[i]);
#pragma unroll
            for (int i = 0; i < 8; ++i) p[i] = swz_xor_add<0x201F>(p[i]);
            if (c == e) {
#pragma unroll
                for (int i = 0; i < 8; ++i) lg[i] += p[i];
            }
        }
    }

    float kp = 0.f;
#pragma unroll
    for (int i = 0; i < 8; ++i) kp += lg[i];
    if (t == 255) l_lds[0][0] = kp;
    asm volatile("" :: "v"(kp));
}

// ---- Pass B: bit-exact recompute of flagged rows (FROZEN, verbatim) ----
__global__ __launch_bounds__(256)
void fixup_k(const float* __restrict__ x,
             const float* __restrict__ w1,
             const float* __restrict__ b1,
             const float* __restrict__ w2,
             const float* __restrict__ b2,
             float* __restrict__ out,
             const unsigned* __restrict__ cntp,
             const unsigned* __restrict__ ids,
             unsigned cap)
{
    const int lane = threadIdx.x & 63;
    const int gw   = (int)((blockIdx.x * 256 + threadIdx.x) >> 6);
    const int nw   = (int)((gridDim.x * 256) >> 6);
    unsigned n = *cntp; if (n > cap) n = cap;
    const int c = lane & 15;
    const int g = lane >> 4;

    for (unsigned wi = gw; wi < n; wi += nw) {
        unsigned row = ids[wi];
        const float* xr = x + (size_t)row * DIN;
        const int nh0 = 128 * g;
        int cols[8];
#pragma unroll
        for (int j = 0; j < 8; ++j)
            cols[j] = nh0 + c * 4 + (j & 3) + ((j >> 2) << 6);

        float a[8];
#pragma unroll
        for (int j = 0; j < 8; ++j) a[j] = 0.f;
        for (int k4 = 0; k4 < 64; ++k4) {
            float4 xv = *(const float4*)(xr + k4 * 4);
            const float* wp = w1 + (size_t)(k4 * 4) * DHID;
#pragma unroll
            for (int j = 0; j < 8; ++j) {
                a[j] = fmaf(xv.x, wp[cols[j]],            a[j]);
                a[j] = fmaf(xv.y, wp[DHID + cols[j]],     a[j]);
                a[j] = fmaf(xv.z, wp[2 * DHID + cols[j]], a[j]);
                a[j] = fmaf(xv.w, wp[3 * DHID + cols[j]], a[j]);
            }
        }
        float h[8];
#pragma unroll
        for (int j = 0; j < 8; ++j) h[j] = fmaxf(a[j] + b1[cols[j]], 0.f);

        float l[NE];
#pragma unroll 1
        for (int e = 0; e < NE; ++e) {
            float p = 0.f;
#pragma unroll
            for (int j = 0; j < 8; ++j)
                p = fmaf(h[j], w2[cols[j] * NE + e], p);
            p += __shfl_xor(p, 1, 64);
            p += __shfl_xor(p, 2, 64);
            p += __shfl_xor(p, 4, 64);
            p += __shfl_xor(p, 8, 64);
            float t0 = __shfl(p, 0 * 16 + e, 64);
            float t1 = __shfl(p, 1 * 16 + e, 64);
            float t2 = __shfl(p, 2 * 16 + e, 64);
            float t3 = __shfl(p, 3 * 16 + e, 64);
            l[e] = (((t0 + t1) + t2) + t3) + b2[e];
        }

        if (lane == 0) {
            float m1 = -INFINITY; int i1 = 0;
#pragma unroll
            for (int e = 0; e < NE; ++e)
                if (l[e] > m1) { m1 = l[e]; i1 = e; }
            float m2 = -INFINITY; int i2 = -1;
#pragma unroll
            for (int e = 0; e < NE; ++e)
                if (e != i1 && l[e] > m2) { m2 = l[e]; i2 = e; }
            float s[NE];
#pragma unroll
            for (int e = 0; e < NE; ++e)
                s[e] = (e == i1 || e == i2) ? l[e] : 0.f;
            float mx = s[0];
#pragma unroll
            for (int e = 1; e < NE; ++e) mx = fmaxf(mx, s[e]);
            float ex[NE];
            float sum = 0.f;
#pragma unroll
            for (int e = 0; e < NE; ++e) { ex[e] = expf(s[e] - mx); sum += ex[e]; }
            float* og = out + (size_t)row * NE;
#pragma unroll
            for (int e = 0; e < NE; ++e) og[e] = ex[e] / sum;
        }
    }
}

extern "C" void kernel_launch(void* const* d_in, const int* in_sizes, int n_in,
                              void* d_out, int out_size, void* d_ws, size_t ws_size,
                              hipStream_t stream) {
    const float* x  = (const float*)d_in[0];
    const float* w1 = (const float*)d_in[1];
    const float* b1 = (const float*)d_in[2];
    const float* w2 = (const float*)d_in[3];
    const float* b2 = (const float*)d_in[4];
    float* outp = (float*)d_out;

    bf16*     w1t = (bf16*)d_ws;
    unsigned* cnt = (unsigned*)((char*)d_ws + (1u << 20));
    unsigned* ids = (unsigned*)((char*)d_ws + (1u << 20) + 64);
    unsigned  cap = 0;
    if (ws_size > (1u << 20) + 64)
        cap = (unsigned)((ws_size - (1u << 20) - 64) / 4);

    hipMemsetAsync((char*)d_ws + (1u << 20), 0, 4, stream);
    split_w1_k<<<dim3(512), dim3(256), 0, stream>>>(w1, w1t);
    router_mfma_k<<<dim3(NROW / ROWS), dim3(256), 0, stream>>>(
        x, b1, w2, b2, outp, w1t, cnt, ids, cap);
    fixup_k<<<dim3(256), dim3(256), 0, stream>>>(
        x, w1, b1, w2, b2, outp, cnt, ids, cap);

    // ---- diagnostic probes (no d_out / cnt / ids writes; timed by rocprof) ----
    pS_k  <<<dim3(8192 * 16), dim3(256), 0, stream>>>(x);
    pL1_k <<<dim3(8192 * 4),  dim3(256), 0, stream>>>(x, b1, w1t);
    pL12_k<<<dim3(8192 * 4),  dim3(256), 0, stream>>>(x, b1, w2, w1t);
}